// Round 1
// baseline (365.140 us; speedup 1.0000x reference)
//
#include <hip/hip_runtime.h>
#include <hip/hip_bf16.h>

// BigramLMParam: Z[b,s,:] = W[inputs[b,s], :]  (one-hot matmul == row gather)
// inputs: [8, 512] int32, W: [8192, 8192] f32, out: [8, 512, 8192] f32

#define VOCAB 8192
#define NTOK  4096   // 8 * 512

// One block per token; 256 threads; each thread copies 8 x float4.
// Row = 8192 floats = 2048 float4 = 256 threads * 8.
__global__ __launch_bounds__(256) void gather_rows_kernel(
    const int* __restrict__ inputs,
    const float* __restrict__ W,
    float* __restrict__ out)
{
    const int tok = blockIdx.x;
    const int row = inputs[tok];            // scalar load, L1/L2 broadcast

    const float4* __restrict__ src = reinterpret_cast<const float4*>(W + (size_t)row * VOCAB);
    float4* __restrict__ dst       = reinterpret_cast<float4*>(out + (size_t)tok * VOCAB);

    const int tid = threadIdx.x;
#pragma unroll
    for (int j = 0; j < 8; ++j) {
        dst[j * 256 + tid] = src[j * 256 + tid];
    }
}

extern "C" void kernel_launch(void* const* d_in, const int* in_sizes, int n_in,
                              void* d_out, int out_size, void* d_ws, size_t ws_size,
                              hipStream_t stream) {
    const int*   inputs = (const int*)d_in[0];   // [8, 512]
    const float* W      = (const float*)d_in[1]; // [8192, 8192]
    float*       out    = (float*)d_out;         // [8, 512, 8192]

    dim3 grid(NTOK);
    dim3 block(256);
    gather_rows_kernel<<<grid, block, 0, stream>>>(inputs, W, out);
}